// Round 1
// baseline (680.811 us; speedup 1.0000x reference)
//
#include <hip/hip_runtime.h>
#include <math.h>

#define N_    8
#define CIN   32
#define COUT  32
#define AUX   128
#define HID   256
#define HW    384
#define MODOUT (COUT*CIN*9)   // 9216

__device__ __forceinline__ float prelu_f(float z, float a) { return z >= 0.f ? z : a * z; }

// ---------------- Kernel A: h, hb, bias (8 blocks, one per sample) ----------
__global__ __launch_bounds__(256) void mlp_head(
    const float* __restrict__ y,
    const float* __restrict__ fc_w1, const float* __restrict__ fc_b1, const float* __restrict__ fc_a,
    const float* __restrict__ b_w1,  const float* __restrict__ b_b1,  const float* __restrict__ b_a,
    const float* __restrict__ b_w2,  const float* __restrict__ b_b2,
    float* __restrict__ ws_h, float* __restrict__ ws_bias)
{
    __shared__ float ly[AUX];
    __shared__ float lhb[HID];
    const int n = blockIdx.x;
    const int j = threadIdx.x;
    if (j < AUX) ly[j] = y[n*AUX + j];
    __syncthreads();
    float ha = fc_b1[j];
    float hb = b_b1[j];
    for (int k = 0; k < AUX; ++k) {
        const float yv = ly[k];
        ha += yv * fc_w1[k*HID + j];
        hb += yv * b_w1[k*HID + j];
    }
    ws_h[n*HID + j] = prelu_f(ha, fc_a[0]);
    lhb[j] = prelu_f(hb, b_a[0]);
    __syncthreads();
    if (j < COUT) {
        float acc = b_b2[j];
        for (int k = 0; k < HID; ++k) acc += lhb[k] * b_w2[k*COUT + j];
        ws_bias[n*COUT + j] = acc;
    }
}

// ------------- Kernel B: modulated weights for all samples (36 blocks) ------
// Output layout: ws_wmod[n][ci*9+tap][co]  (co contiguous for conv float4 reads)
__global__ __launch_bounds__(256) void mod_weights(
    const float* __restrict__ ws_h,
    const float* __restrict__ fc_w2, const float* __restrict__ fc_b2,
    const float* __restrict__ weight, float* __restrict__ ws_wmod)
{
    __shared__ float lh[N_*HID];
    for (int i = threadIdx.x; i < N_*HID; i += 256) lh[i] = ws_h[i];
    __syncthreads();
    const int m = blockIdx.x * 256 + threadIdx.x;   // 0..9215
    const float b = fc_b2[m];
    float acc[N_];
#pragma unroll
    for (int n = 0; n < N_; ++n) acc[n] = b;
    for (int j = 0; j < HID; ++j) {
        const float w = fc_w2[j*MODOUT + m];
#pragma unroll
        for (int n = 0; n < N_; ++n) acc[n] += lh[n*HID + j] * w;
    }
    const int co = m / 288;          // weight is [co][ci][kh][kw]
    const int r  = m - co * 288;     // ci*9 + tap
    const float wv = weight[m];
#pragma unroll
    for (int n = 0; n < N_; ++n) {
        const float mod = 1.f / (1.f + __expf(-acc[n]));
        ws_wmod[n*MODOUT + r*COUT + co] = mod * wv;
    }
}

// ---------------- Kernel C: modulated conv, fp32 direct --------------------
// Block: 32x16 spatial tile, all 32 cout. 256 threads:
//   g = tid>>6 (cout group of 8, one per wave -> wave-uniform weight reads)
//   s = tid&63: r = s>>2 (row 0..15), c0 = (s&3)*8 (8-px strip)
#define TW 32
#define TH 16
__global__ __launch_bounds__(256) void conv_mod(
    const float* __restrict__ x,
    const float* __restrict__ wmod, const float* __restrict__ bias,
    float* __restrict__ out)
{
    __shared__ float lw[MODOUT];        // [ci][tap][co], 36 KB
    __shared__ float lx[8][18][36];     // 8-ci slab + halo; stride 36 keeps float4 align

    const int n  = blockIdx.z;
    const int gh = blockIdx.y * TH;
    const int gw = blockIdx.x * TW;
    const int tid = threadIdx.x;
    const int g  = tid >> 6;
    const int s  = tid & 63;
    const int r  = s >> 2;
    const int c0 = (s & 3) * 8;

    const float* wsrc = wmod + n*MODOUT;
    for (int i = tid; i < MODOUT; i += 256) lw[i] = wsrc[i];

    float acc[8][8];
#pragma unroll
    for (int a = 0; a < 8; ++a)
#pragma unroll
        for (int b = 0; b < 8; ++b) acc[a][b] = 0.f;

    for (int cc = 0; cc < 4; ++cc) {
        __syncthreads();
        // stage 8 input channels with halo, zero-padded
        for (int i = tid; i < 8*18*34; i += 256) {
            const int ci  = i / 612;
            const int rem = i - ci*612;
            const int rr  = rem / 34;
            const int c   = rem - rr*34;
            const int grow = gh + rr - 1;
            const int gcol = gw + c  - 1;
            float v = 0.f;
            if ((unsigned)grow < HW && (unsigned)gcol < HW)
                v = x[((size_t)(n*CIN + cc*8 + ci)*HW + grow)*HW + gcol];
            lx[ci][rr][c] = v;
        }
        __syncthreads();
#pragma unroll 1
        for (int ci = 0; ci < 8; ++ci) {
#pragma unroll
            for (int kh = 0; kh < 3; ++kh) {
                const float4* xp = reinterpret_cast<const float4*>(&lx[ci][r + kh][c0]);
                const float4 xa = xp[0], xb = xp[1], xc = xp[2];
                const float xv[12] = {xa.x,xa.y,xa.z,xa.w, xb.x,xb.y,xb.z,xb.w, xc.x,xc.y,xc.z,xc.w};
#pragma unroll
                for (int kw = 0; kw < 3; ++kw) {
                    const float4* wp = reinterpret_cast<const float4*>(
                        &lw[((cc*8 + ci)*9 + kh*3 + kw)*COUT + g*8]);
                    const float4 wa = wp[0], wb = wp[1];
                    const float wv[8] = {wa.x,wa.y,wa.z,wa.w, wb.x,wb.y,wb.z,wb.w};
#pragma unroll
                    for (int co = 0; co < 8; ++co)
#pragma unroll
                        for (int p = 0; p < 8; ++p)
                            acc[co][p] += wv[co] * xv[kw + p];
                }
            }
        }
    }

#pragma unroll
    for (int co = 0; co < 8; ++co) {
        const int gco = g*8 + co;
        const float b = bias[n*COUT + gco];
        float* op = out + (((size_t)(n*COUT + gco)*HW + gh + r)*HW + gw + c0);
        float4 o0 = make_float4(acc[co][0]+b, acc[co][1]+b, acc[co][2]+b, acc[co][3]+b);
        float4 o1 = make_float4(acc[co][4]+b, acc[co][5]+b, acc[co][6]+b, acc[co][7]+b);
        reinterpret_cast<float4*>(op)[0] = o0;
        reinterpret_cast<float4*>(op)[1] = o1;
    }
}

extern "C" void kernel_launch(void* const* d_in, const int* in_sizes, int n_in,
                              void* d_out, int out_size, void* d_ws, size_t ws_size,
                              hipStream_t stream) {
    const float* x     = (const float*)d_in[0];
    const float* y     = (const float*)d_in[1];
    const float* weight= (const float*)d_in[2];
    const float* fc_w1 = (const float*)d_in[3];
    const float* fc_b1 = (const float*)d_in[4];
    const float* fc_a  = (const float*)d_in[5];
    const float* fc_w2 = (const float*)d_in[6];
    const float* fc_b2 = (const float*)d_in[7];
    const float* b_w1  = (const float*)d_in[8];
    const float* b_b1  = (const float*)d_in[9];
    const float* b_a   = (const float*)d_in[10];
    const float* b_w2  = (const float*)d_in[11];
    const float* b_b2  = (const float*)d_in[12];
    float* out = (float*)d_out;

    float* ws      = (float*)d_ws;
    float* ws_wmod = ws;                       // 73728 floats
    float* ws_h    = ws + MODOUT*N_;           // 2048 floats
    float* ws_bias = ws_h + N_*HID;            // 256 floats

    mlp_head<<<N_, 256, 0, stream>>>(y, fc_w1, fc_b1, fc_a, b_w1, b_b1, b_a,
                                     b_w2, b_b2, ws_h, ws_bias);
    mod_weights<<<MODOUT/256, 256, 0, stream>>>(ws_h, fc_w2, fc_b2, weight, ws_wmod);
    conv_mod<<<dim3(HW/TW, HW/TH, N_), 256, 0, stream>>>(x, ws_wmod, ws_bias, out);
}

// Round 2
// 329.502 us; speedup vs baseline: 2.0662x; 2.0662x over previous
//
#include <hip/hip_runtime.h>
#include <math.h>

#define N_    8
#define CIN   32
#define COUT  32
#define AUX   128
#define HID   256
#define HWD   384
#define HW2   (HWD*HWD)
#define MODOUT (COUT*CIN*9)   // 9216

typedef short s8v  __attribute__((ext_vector_type(8)));   // 8 bf16 (4 VGPRs)
typedef float f16v __attribute__((ext_vector_type(16)));  // 32x32 C/D frag

__device__ __forceinline__ unsigned short f2b(float f) {  // fp32 -> bf16 RNE
    unsigned u = __float_as_uint(f);
    u += 0x7FFF + ((u >> 16) & 1);
    return (unsigned short)(u >> 16);
}
__device__ __forceinline__ float prelu_f(float z, float a) { return z >= 0.f ? z : a * z; }

// ---------------- Kernel A: h, hb, bias (8 blocks) -------------------------
__global__ __launch_bounds__(256) void mlp_head(
    const float* __restrict__ y,
    const float* __restrict__ fc_w1, const float* __restrict__ fc_b1, const float* __restrict__ fc_a,
    const float* __restrict__ b_w1,  const float* __restrict__ b_b1,  const float* __restrict__ b_a,
    const float* __restrict__ b_w2,  const float* __restrict__ b_b2,
    float* __restrict__ ws_h, float* __restrict__ ws_bias)
{
    __shared__ float ly[AUX];
    __shared__ float lhb[HID];
    const int n = blockIdx.x;
    const int j = threadIdx.x;
    if (j < AUX) ly[j] = y[n*AUX + j];
    __syncthreads();
    float ha = fc_b1[j];
    float hb = b_b1[j];
    for (int k = 0; k < AUX; ++k) {
        const float yv = ly[k];
        ha += yv * fc_w1[k*HID + j];
        hb += yv * b_w1[k*HID + j];
    }
    ws_h[n*HID + j] = prelu_f(ha, fc_a[0]);
    lhb[j] = prelu_f(hb, b_a[0]);
    __syncthreads();
    if (j < COUT) {
        float acc = b_b2[j];
        for (int k = 0; k < HID; ++k) acc += lhb[k] * b_w2[k*COUT + j];
        ws_bias[n*COUT + j] = acc;
    }
}

// ------- Kernel B: modulated bf16 weights, K split 8 ways (288 blocks) -----
// out layout: wmod[n][tap][co][ci]  (ci contiguous -> A-frag dwordx4 loads)
__global__ __launch_bounds__(256) void mod_weights(
    const float* __restrict__ ws_h,
    const float* __restrict__ fc_w2, const float* __restrict__ fc_b2,
    const float* __restrict__ weight, unsigned short* __restrict__ wmod)
{
    __shared__ float lh[N_*HID];        // 8 KB
    __shared__ float red[8][32][N_];    // [jc][ml][n], 8 KB
    const int tid = threadIdx.x;
    for (int i = tid; i < N_*HID; i += 256) lh[i] = ws_h[i];
    __syncthreads();
    const int ml = tid & 31;
    const int jc = tid >> 5;
    const int m  = blockIdx.x * 32 + ml;
    float acc[N_];
#pragma unroll
    for (int n = 0; n < N_; ++n) acc[n] = 0.f;
    for (int jj = 0; jj < 32; ++jj) {
        const int j = jc*32 + jj;
        const float w = fc_w2[j*MODOUT + m];
#pragma unroll
        for (int n = 0; n < N_; ++n) acc[n] += lh[n*HID + j] * w;
    }
#pragma unroll
    for (int n = 0; n < N_; ++n) red[jc][ml][n] = acc[n];
    __syncthreads();
    const int nn = jc;                  // reuse thread as (ml, n)
    float s = fc_b2[m];
#pragma unroll
    for (int k = 0; k < 8; ++k) s += red[k][ml][nn];
    const float mod = 1.f / (1.f + __expf(-s));
    const float v = mod * weight[m];
    const int co = m / 288, r = m - co*288;
    const int ci = r / 9,  tap = r - ci*9;
    wmod[((nn*9 + tap)*COUT + co)*CIN + ci] = f2b(v);
}

// ---------------- Kernel C: conv as 9 shifted 1x1 GEMMs via MFMA -----------
// Tile: 8 rows x 64 cols x all 32 cout per block; 4 waves, each wave owns
// 2 rows x 2 col-groups (4 C-frags). A = W[co][ci] (M=cout), B = X[ci][px]
// (N=32 contiguous cols) -> D col=lane&31=pixel -> coalesced dword stores.
#define TH    8
#define TCOL  64
#define LROWS 10
#define LCOLS 72

__global__ __launch_bounds__(256, 2) void conv_mfma(
    const float* __restrict__ x,
    const unsigned short* __restrict__ wmod,
    const float* __restrict__ bias,
    float* __restrict__ out)
{
    __shared__ __align__(16) unsigned short lx[LROWS*LCOLS*16];  // 23040 B

    const int tid = threadIdx.x;
    const int n   = blockIdx.z;
    const int gh  = blockIdx.y * TH;
    const int gw  = blockIdx.x * TCOL;
    const int lane = tid & 63;
    const int wv  = tid >> 6;     // wave 0..3
    const int lm  = lane & 31;    // co (A) / pixel (B,D) lane index
    const int h   = lane >> 5;    // k-oct selector

    f16v acc[4];
#pragma unroll
    for (int g = 0; g < 4; ++g)
#pragma unroll
        for (int r = 0; r < 16; ++r) acc[g][r] = 0.f;

    // per-reg bias (co depends on reg and h only)
    float br[16];
#pragma unroll
    for (int r = 0; r < 16; ++r) {
        const int co = (r & 3) + 8*(r >> 2) + 4*h;
        br[r] = bias[n*COUT + co];
    }

    for (int cc = 0; cc < 2; ++cc) {          // two K=16 channel halves
        if (cc) __syncthreads();              // protect lx before restage
        // ---- stage x[cc*16 .. +15] as bf16 [row][col][ci16] ----
        for (int it = tid; it < 360; it += 256) {
            const int o   = it & 1;           // ci oct (8 channels)
            const int rc  = it >> 1;
            const int row = rc / 18;
            const int q   = rc - row*18;      // col quad
            const int gr  = gh + row - 1;
            const int gc  = gw + q*4 - 4;
            float va[8][4];
            if ((unsigned)gr < HWD && (unsigned)gc < HWD) {
                const float* xb = x + ((size_t)(n*CIN + cc*16 + o*8)*HWD + gr)*HWD + gc;
#pragma unroll
                for (int ci = 0; ci < 8; ++ci) {
                    const float4 t = *(const float4*)(xb + (size_t)ci*HW2);
                    va[ci][0] = t.x; va[ci][1] = t.y; va[ci][2] = t.z; va[ci][3] = t.w;
                }
            } else {
#pragma unroll
                for (int ci = 0; ci < 8; ++ci)
                    va[ci][0] = va[ci][1] = va[ci][2] = va[ci][3] = 0.f;
            }
#pragma unroll
            for (int c = 0; c < 4; ++c) {
                const unsigned w0 = (unsigned)f2b(va[0][c]) | ((unsigned)f2b(va[1][c]) << 16);
                const unsigned w1 = (unsigned)f2b(va[2][c]) | ((unsigned)f2b(va[3][c]) << 16);
                const unsigned w2 = (unsigned)f2b(va[4][c]) | ((unsigned)f2b(va[5][c]) << 16);
                const unsigned w3 = (unsigned)f2b(va[6][c]) | ((unsigned)f2b(va[7][c]) << 16);
                const int idx = ((row*LCOLS + q*4 + c)*16) + o*8;   // ushort index
                *(int4*)&lx[idx] = make_int4((int)w0, (int)w1, (int)w2, (int)w3);
            }
        }
        __syncthreads();

        // ---- A-frags: 9 taps of W[co][k], k = cc*16 + h*8 + j (L2-hot) ----
        s8v a[9];
#pragma unroll
        for (int t = 0; t < 9; ++t)
            a[t] = *(const s8v*)&wmod[(((n*9 + t)*COUT + lm)*CIN) + cc*16 + h*8];

        // ---- 4 groups x 9 taps of MFMA ----
#pragma unroll
        for (int g = 0; g < 4; ++g) {
            const int rr   = 2*wv + (g & 1);
            const int cg   = g >> 1;
            const int colb = cg*32 + lm + 3;   // LDS col 0 == global col gw-4
#pragma unroll
            for (int kh = 0; kh < 3; ++kh) {
                const int rowb = (rr + kh) * LCOLS;
#pragma unroll
                for (int kw = 0; kw < 3; ++kw) {
                    const s8v b = *(const s8v*)&lx[(rowb + colb + kw)*16 + h*8];
                    acc[g] = __builtin_amdgcn_mfma_f32_32x32x16_bf16(a[kh*3 + kw], b, acc[g], 0, 0, 0);
                }
            }
        }
    }

    // ---- epilogue: bias + coalesced dword stores ----
#pragma unroll
    for (int g = 0; g < 4; ++g) {
        const int rr = 2*wv + (g & 1);
        const int cg = g >> 1;
        float* ob = out + (size_t)(n*COUT)*HW2 + (size_t)(gh + rr)*HWD + gw + cg*32 + lm;
#pragma unroll
        for (int r = 0; r < 16; ++r) {
            const int co = (r & 3) + 8*(r >> 2) + 4*h;
            ob[(size_t)co*HW2] = acc[g][r] + br[r];
        }
    }
}

extern "C" void kernel_launch(void* const* d_in, const int* in_sizes, int n_in,
                              void* d_out, int out_size, void* d_ws, size_t ws_size,
                              hipStream_t stream) {
    const float* x     = (const float*)d_in[0];
    const float* y     = (const float*)d_in[1];
    const float* weight= (const float*)d_in[2];
    const float* fc_w1 = (const float*)d_in[3];
    const float* fc_b1 = (const float*)d_in[4];
    const float* fc_a  = (const float*)d_in[5];
    const float* fc_w2 = (const float*)d_in[6];
    const float* fc_b2 = (const float*)d_in[7];
    const float* b_w1  = (const float*)d_in[8];
    const float* b_b1  = (const float*)d_in[9];
    const float* b_a   = (const float*)d_in[10];
    const float* b_w2  = (const float*)d_in[11];
    const float* b_b2  = (const float*)d_in[12];
    float* out = (float*)d_out;

    unsigned short* ws_wmod = (unsigned short*)d_ws;                 // 147456 B
    float* ws_h    = (float*)((char*)d_ws + (size_t)MODOUT*N_*2);    // 2048 f
    float* ws_bias = ws_h + N_*HID;                                  // 256 f

    mlp_head<<<N_, 256, 0, stream>>>(y, fc_w1, fc_b1, fc_a, b_w1, b_b1, b_a,
                                     b_w2, b_b2, ws_h, ws_bias);
    mod_weights<<<MODOUT/32, 256, 0, stream>>>(ws_h, fc_w2, fc_b2, weight, ws_wmod);
    conv_mfma<<<dim3(HWD/TCOL, HWD/TH, N_), 256, 0, stream>>>(x, ws_wmod, ws_bias, out);
}